// Round 1
// baseline (3716.031 us; speedup 1.0000x reference)
//
#include <hip/hip_runtime.h>
#include <math.h>

#define BM 64
#define BN 64
#define BK 16

// Generic fp32 tiled GEMM: C[M,N] = A[M,K] @ B[K,N]. M must be multiple of 64.
__global__ __launch_bounds__(256) void gemm_nn(const float* __restrict__ A,
                                               const float* __restrict__ B,
                                               float* __restrict__ C,
                                               int M, int N, int K,
                                               int lda, int ldb, int ldc) {
    __shared__ float As[BK][BM + 4];
    __shared__ float Bs[BK][BN + 4];
    int bm = blockIdx.x * BM;
    int bn = blockIdx.y * BN;
    int tid = threadIdx.x;
    int tm = tid >> 4;      // 0..15
    int tn = tid & 15;      // 0..15
    float acc[4][4] = {};
    for (int k0 = 0; k0 < K; k0 += BK) {
        // A tile: BM x BK, k fastest across lanes
#pragma unroll
        for (int i = 0; i < 4; i++) {
            int flat = tid + i * 256;
            int m = flat >> 4, kk = flat & 15;
            int gk = k0 + kk;
            As[kk][m] = (gk < K) ? A[(size_t)(bm + m) * lda + gk] : 0.f;
        }
        // B tile: BK x BN, n fastest across lanes
#pragma unroll
        for (int i = 0; i < 4; i++) {
            int flat = tid + i * 256;
            int kk = flat >> 6, n = flat & 63;
            int gk = k0 + kk;
            float vb = 0.f;
            if (gk < K && (bn + n) < N) vb = B[(size_t)gk * ldb + bn + n];
            Bs[kk][n] = vb;
        }
        __syncthreads();
#pragma unroll
        for (int kk = 0; kk < BK; kk++) {
            float4 a4 = *(const float4*)&As[kk][tm * 4];
            float4 b4 = *(const float4*)&Bs[kk][tn * 4];
            float a[4] = {a4.x, a4.y, a4.z, a4.w};
            float b[4] = {b4.x, b4.y, b4.z, b4.w};
#pragma unroll
            for (int i = 0; i < 4; i++)
#pragma unroll
                for (int j = 0; j < 4; j++) acc[i][j] = fmaf(a[i], b[j], acc[i][j]);
        }
        __syncthreads();
    }
#pragma unroll
    for (int i = 0; i < 4; i++) {
        int m = bm + tm * 4 + i;
#pragma unroll
        for (int j = 0; j < 4; j++) {
            int n = bn + tn * 4 + j;
            if (n < N) C[(size_t)m * ldc + n] = acc[i][j];
        }
    }
}

#define TT 46

__device__ __forceinline__ float sigf(float x) { return 1.f / (1.f + expf(-x)); }

// LayerNorm LSTM recurrence. 64 blocks: blocks 0..31 = lstm1 (4 batch rows each),
// 32..63 = lstm2. Input contribution Zx precomputed; here only h @ W_h + pointwise.
__global__ __launch_bounds__(256) void lstm_kernel(
    const float* __restrict__ Zx1, const float* __restrict__ Zx2,
    const float* __restrict__ W1, const float* __restrict__ W2,
    const float* __restrict__ lng1, const float* __restrict__ lnb1,
    const float* __restrict__ lng2, const float* __restrict__ lnb2,
    float* __restrict__ o1, float* __restrict__ o2) {
    int lstm = blockIdx.x >> 5;
    int r0 = (blockIdx.x & 31) * 4;
    const float* Zx = lstm ? Zx2 : Zx1;
    const float* Wh = (lstm ? W2 : W1) + 300 * 512;  // rows 300..427
    const float* g  = lstm ? lng2 : lng1;
    const float* bb = lstm ? lnb2 : lnb1;
    float* obuf = lstm ? o2 : o1;

    __shared__ __align__(16) float hs[4][128];
    __shared__ __align__(16) float cs[4][128];
    __shared__ __align__(16) float zb[4][512];
    __shared__ float mu[4][4], rs[4][4], cmu[4], crs[4];

    int tid = threadIdx.x;
    for (int i = tid; i < 512; i += 256) {
        hs[i >> 7][i & 127] = 0.f;
        cs[i >> 7][i & 127] = 0.f;
    }
    __syncthreads();

    for (int t = 0; t < TT; t++) {
        // ---- phase 1: z = Zx[:,t,:] + h @ Wh ----
        int c0 = tid * 2;
        float2 acc[4];
#pragma unroll
        for (int r = 0; r < 4; r++)
            acc[r] = *(const float2*)&Zx[((size_t)(r0 + r) * TT + t) * 512 + c0];
        for (int k = 0; k < 128; k += 4) {
            float4 h4[4];
#pragma unroll
            for (int r = 0; r < 4; r++) h4[r] = *(const float4*)&hs[r][k];
#pragma unroll
            for (int kk = 0; kk < 4; kk++) {
                float2 w = *(const float2*)&Wh[(size_t)(k + kk) * 512 + c0];
#pragma unroll
                for (int r = 0; r < 4; r++) {
                    float hk = ((const float*)&h4[r])[kk];
                    acc[r].x = fmaf(hk, w.x, acc[r].x);
                    acc[r].y = fmaf(hk, w.y, acc[r].y);
                }
            }
        }
#pragma unroll
        for (int r = 0; r < 4; r++) {
            zb[r][c0] = acc[r].x;
            zb[r][c0 + 1] = acc[r].y;
        }
        __syncthreads();

        // ---- phase 2: LN stats per (row, gate) — 16 groups of 16 lanes ----
        {
            int grp = tid >> 4;
            int row = grp >> 2, gate = grp & 3;
            int l = tid & 15;
            float s = 0.f, ss = 0.f;
#pragma unroll
            for (int j = 0; j < 8; j++) {
                float v = zb[row][gate * 128 + l + j * 16];
                s += v; ss += v * v;
            }
#pragma unroll
            for (int off = 1; off < 16; off <<= 1) {
                s += __shfl_xor(s, off);
                ss += __shfl_xor(ss, off);
            }
            if (l == 0) {
                float m_ = s * (1.f / 128.f);
                mu[row][gate] = m_;
                rs[row][gate] = rsqrtf(ss * (1.f / 128.f) - m_ * m_ + 1e-12f);
            }
        }
        __syncthreads();

        // ---- phase 3: gates + cell update ----
        float ogate[2];
#pragma unroll
        for (int ii = 0; ii < 2; ii++) {
            int idx = tid + ii * 256;
            int row = idx >> 7, col = idx & 127;
            float i_g = (zb[row][col]       - mu[row][0]) * rs[row][0] * g[0 * 128 + col] + bb[0 * 128 + col];
            float j_g = (zb[row][128 + col] - mu[row][1]) * rs[row][1] * g[1 * 128 + col] + bb[1 * 128 + col];
            float f_g = (zb[row][256 + col] - mu[row][2]) * rs[row][2] * g[2 * 128 + col] + bb[2 * 128 + col];
            float o_g = (zb[row][384 + col] - mu[row][3]) * rs[row][3] * g[3 * 128 + col] + bb[3 * 128 + col];
            float nc = cs[row][col] * sigf(f_g + 1.f) + sigf(i_g) * fmaxf(j_g, 0.f);
            cs[row][col] = nc;
            ogate[ii] = o_g;
        }
        __syncthreads();

        // ---- phase 4: LN stats over new c, wave w handles row w ----
        {
            int w = tid >> 6, l = tid & 63;
            float v0 = cs[w][l], v1 = cs[w][l + 64];
            float s = v0 + v1, ss = v0 * v0 + v1 * v1;
#pragma unroll
            for (int off = 1; off < 64; off <<= 1) {
                s += __shfl_xor(s, off);
                ss += __shfl_xor(ss, off);
            }
            if (l == 0) {
                float m_ = s * (1.f / 128.f);
                cmu[w] = m_;
                crs[w] = rsqrtf(ss * (1.f / 128.f) - m_ * m_ + 1e-12f);
            }
        }
        __syncthreads();

        // ---- phase 5: h = relu(LN(c)) * sigmoid(o) ----
#pragma unroll
        for (int ii = 0; ii < 2; ii++) {
            int idx = tid + ii * 256;
            int row = idx >> 7, col = idx & 127;
            float lnc = (cs[row][col] - cmu[row]) * crs[row] * g[4 * 128 + col] + bb[4 * 128 + col];
            float hv = fmaxf(lnc, 0.f) * sigf(ogate[ii]);
            hs[row][col] = hv;
            obuf[((size_t)(r0 + row) * TT + t) * 128 + col] = hv;
        }
        __syncthreads();
    }
}

// Attention: softmax(o.v) over T, ctx, then dense(512)+relu into acat.
// 256 blocks: blocks 0..127 lstm1 batch b, 128..255 lstm2.
__global__ __launch_bounds__(256) void attn_kernel(
    const float* __restrict__ o1, const float* __restrict__ o2,
    const float* __restrict__ v1, const float* __restrict__ v2,
    const float* __restrict__ Wo1, const float* __restrict__ Wo2,
    const float* __restrict__ bo1, const float* __restrict__ bo2,
    float* __restrict__ acat) {
    int lstm = blockIdx.x >> 7;
    int b = blockIdx.x & 127;
    const float* o  = (lstm ? o2 : o1) + (size_t)b * TT * 128;
    const float* v  = lstm ? v2 : v1;
    const float* Wo = lstm ? Wo2 : Wo1;
    const float* bo = lstm ? bo2 : bo1;
    __shared__ float sc[64];
    __shared__ float ctx[128];
    int tid = threadIdx.x;
    if (tid < TT) {
        float s = 0.f;
        for (int h = 0; h < 128; h++) s = fmaf(o[tid * 128 + h], v[h], s);
        sc[tid] = s;
    }
    __syncthreads();
    if (tid < 64) {
        float x = (tid < TT) ? sc[tid] : -1e30f;
        float m = x;
#pragma unroll
        for (int off = 1; off < 64; off <<= 1) m = fmaxf(m, __shfl_xor(m, off));
        float e = (tid < TT) ? expf(x - m) : 0.f;
        float s = e;
#pragma unroll
        for (int off = 1; off < 64; off <<= 1) s += __shfl_xor(s, off);
        if (tid < TT) sc[tid] = e / s;
    }
    __syncthreads();
    if (tid < 128) {
        float s = 0.f;
        for (int t = 0; t < TT; t++) s = fmaf(sc[t], o[t * 128 + tid], s);
        ctx[tid] = s;
    }
    __syncthreads();
#pragma unroll
    for (int j = 0; j < 2; j++) {
        int n = tid * 2 + j;
        float s = bo[n];
        for (int h = 0; h < 128; h++) s = fmaf(ctx[h], Wo[h * 512 + n], s);
        acat[(size_t)b * 1024 + lstm * 512 + n] = fmaxf(s, 0.f);
    }
}

// hidden = relu(acat @ W_h + b_h); logits = hidden @ W_out + b_out
__global__ __launch_bounds__(256) void final_kernel(
    const float* __restrict__ acat, const float* __restrict__ Wh,
    const float* __restrict__ bh, const float* __restrict__ Wout,
    const float* __restrict__ bout, float* __restrict__ out) {
    int b = blockIdx.x;
    __shared__ float ain[1024];
    __shared__ float hid[512];
    __shared__ float red[4];
    int tid = threadIdx.x;
    for (int i = tid; i < 1024; i += 256) ain[i] = acat[(size_t)b * 1024 + i];
    __syncthreads();
#pragma unroll
    for (int j = 0; j < 2; j++) {
        int n = tid * 2 + j;
        float s = bh[n];
        for (int k = 0; k < 1024; k++) s = fmaf(ain[k], Wh[(size_t)k * 512 + n], s);
        hid[n] = fmaxf(s, 0.f);
    }
    __syncthreads();
    for (int j = 0; j < 2; j++) {
        float p = 0.f;
        for (int k = tid; k < 512; k += 256) p = fmaf(hid[k], Wout[k * 2 + j], p);
#pragma unroll
        for (int off = 1; off < 64; off <<= 1) p += __shfl_xor(p, off);
        if ((tid & 63) == 0) red[tid >> 6] = p;
        __syncthreads();
        if (tid == 0) out[b * 2 + j] = red[0] + red[1] + red[2] + red[3] + bout[j];
        __syncthreads();
    }
}

extern "C" void kernel_launch(void* const* d_in, const int* in_sizes, int n_in,
                              void* d_out, int out_size, void* d_ws, size_t ws_size,
                              hipStream_t stream) {
    const float* x1      = (const float*)d_in[0];
    const float* x2      = (const float*)d_in[1];
    const float* embed1  = (const float*)d_in[2];
    const float* embed2  = (const float*)d_in[3];
    const float* W_lstm1 = (const float*)d_in[4];
    const float* W_lstm2 = (const float*)d_in[5];
    const float* lng1    = (const float*)d_in[6];
    const float* lnb1    = (const float*)d_in[7];
    const float* lng2    = (const float*)d_in[8];
    const float* lnb2    = (const float*)d_in[9];
    const float* attn_v1 = (const float*)d_in[10];
    const float* attn_Wo1= (const float*)d_in[11];
    const float* attn_bo1= (const float*)d_in[12];
    const float* attn_v2 = (const float*)d_in[13];
    const float* attn_Wo2= (const float*)d_in[14];
    const float* attn_bo2= (const float*)d_in[15];
    const float* W_h     = (const float*)d_in[16];
    const float* b_h     = (const float*)d_in[17];
    const float* W_out   = (const float*)d_in[18];
    const float* b_out   = (const float*)d_in[19];
    float* out = (float*)d_out;

    // Workspace layout (floats)
    float* ws    = (float*)d_ws;
    float* e_buf = ws;                  // 5888*300  = 1,766,400
    float* Zx1   = e_buf + 1766400;     // 5888*512  = 3,014,656
    float* Zx2   = Zx1 + 3014656;       // 3,014,656
    float* o1    = Zx2 + 3014656;       // 128*46*128 = 753,664
    float* o2    = o1 + 753664;         // 753,664
    float* acat  = o2 + 753664;         // 128*1024 = 131,072
    // total ~9.4M floats = ~37.7 MB

    dim3 blk(256);
    // e1 = x1 @ embed1 ; Zx1 = e1 @ W_lstm1[0:300,:]
    gemm_nn<<<dim3(92, 5), blk, 0, stream>>>(x1, embed1, e_buf, 5888, 300, 8150, 8150, 300, 300);
    gemm_nn<<<dim3(92, 8), blk, 0, stream>>>(e_buf, W_lstm1, Zx1, 5888, 512, 300, 300, 512, 512);
    // e2 = x2 @ embed2 ; Zx2 = e2 @ W_lstm2[0:300,:]  (e_buf reused)
    gemm_nn<<<dim3(92, 5), blk, 0, stream>>>(x2, embed2, e_buf, 5888, 300, 8150, 8150, 300, 300);
    gemm_nn<<<dim3(92, 8), blk, 0, stream>>>(e_buf, W_lstm2, Zx2, 5888, 512, 300, 300, 512, 512);
    // recurrences (both LSTMs in one launch)
    lstm_kernel<<<64, blk, 0, stream>>>(Zx1, Zx2, W_lstm1, W_lstm2,
                                        lng1, lnb1, lng2, lnb2, o1, o2);
    // attention + first dense
    attn_kernel<<<256, blk, 0, stream>>>(o1, o2, attn_v1, attn_v2,
                                         attn_Wo1, attn_Wo2, attn_bo1, attn_bo2, acat);
    // final MLP
    final_kernel<<<128, blk, 0, stream>>>(acat, W_h, b_h, W_out, b_out, out);
}

// Round 2
// 1421.025 us; speedup vs baseline: 2.6150x; 2.6150x over previous
//
#include <hip/hip_runtime.h>
#include <math.h>

typedef short bf16x8 __attribute__((ext_vector_type(8)));
typedef float f32x4 __attribute__((ext_vector_type(4)));

__device__ __forceinline__ ushort f2bf(float f) {
    unsigned u = __float_as_uint(f);
    u = u + 0x7FFFu + ((u >> 16) & 1u);
    return (ushort)(u >> 16);
}
__device__ __forceinline__ float bf2f(ushort h) {
    return __uint_as_float(((unsigned)h) << 16);
}

#define LSTRIDE 40   // LDS row stride in bf16 elements (32 data + 8 pad)

// ---------------------------------------------------------------------------
// Stage 1: EWt = (embed[0:8150,0:300] @ W[0:300,0:512])^T as bf16 hi/lo,
// shape [512][8192] (k-dim padded 8150->8192 with zeros, K=300 padded to 320).
// Split-bf16 (hi*hi + hi*lo + lo*hi) for near-fp32 accuracy.
// grid (64 m-blocks of 128, 4 n-cols of 128), 512 threads.
// ---------------------------------------------------------------------------
__global__ __launch_bounds__(512, 4) void ew_kernel(
    const float* __restrict__ embed, const float* __restrict__ W,
    ushort* __restrict__ EWt_hi, ushort* __restrict__ EWt_lo) {
    __shared__ ushort Ah[128 * LSTRIDE], Al[128 * LSTRIDE];
    __shared__ ushort Bh[128 * LSTRIDE], Bl[128 * LSTRIDE];
    int bm = blockIdx.x * 128;     // embed-row block (k of EWt)
    int bn = blockIdx.y * 128;     // output-col block
    int tid = threadIdx.x;
    int lane = tid & 63, w = tid >> 6;
    int quad = lane >> 4, l16 = lane & 15;
    int wm = (w & 3) * 32, wn = (w >> 2) * 64;

    f32x4 acc[2][4];
#pragma unroll
    for (int a = 0; a < 2; a++)
#pragma unroll
        for (int b = 0; b < 4; b++) acc[a][b] = (f32x4){0.f, 0.f, 0.f, 0.f};

    for (int k0 = 0; k0 < 320; k0 += 32) {
        // A staging: embed[bm+m][k0..k0+31] -> hi/lo bf16, row-major stride 40
#pragma unroll
        for (int r = 0; r < 2; r++) {
            int flat = tid + r * 512;              // 0..1023
            int m = flat >> 3, kk4 = (flat & 7) * 4;
            int gm = bm + m, gk = k0 + kk4;
            float4 v = make_float4(0.f, 0.f, 0.f, 0.f);
            if (gm < 8150 && gk < 300) v = *(const float4*)&embed[(size_t)gm * 300 + gk];
            ushort4 h, l;
            h.x = f2bf(v.x); l.x = f2bf(v.x - bf2f(h.x));
            h.y = f2bf(v.y); l.y = f2bf(v.y - bf2f(h.y));
            h.z = f2bf(v.z); l.z = f2bf(v.z - bf2f(h.z));
            h.w = f2bf(v.w); l.w = f2bf(v.w - bf2f(h.w));
            *(ushort4*)&Ah[m * LSTRIDE + kk4] = h;
            *(ushort4*)&Al[m * LSTRIDE + kk4] = l;
        }
        // B staging: W[k][bn+n] -> transposed LDS Bt[n][k] hi/lo
#pragma unroll
        for (int p = 0; p < 8; p++) {
            int kk = (tid >> 7) + p * 4;           // 0..31
            int n = tid & 127;
            int gk = k0 + kk;
            float v = (gk < 300) ? W[(size_t)gk * 512 + bn + n] : 0.f;
            ushort h = f2bf(v);
            Bh[n * LSTRIDE + kk] = h;
            Bl[n * LSTRIDE + kk] = f2bf(v - bf2f(h));
        }
        __syncthreads();
        bf16x8 a_h[2], a_l[2];
#pragma unroll
        for (int mf = 0; mf < 2; mf++) {
            int row = wm + mf * 16 + l16;
            a_h[mf] = *(const bf16x8*)&Ah[row * LSTRIDE + quad * 8];
            a_l[mf] = *(const bf16x8*)&Al[row * LSTRIDE + quad * 8];
        }
#pragma unroll
        for (int nf = 0; nf < 4; nf++) {
            int col = wn + nf * 16 + l16;
            bf16x8 b_h = *(const bf16x8*)&Bh[col * LSTRIDE + quad * 8];
            bf16x8 b_l = *(const bf16x8*)&Bl[col * LSTRIDE + quad * 8];
#pragma unroll
            for (int mf = 0; mf < 2; mf++) {
                acc[mf][nf] = __builtin_amdgcn_mfma_f32_16x16x32_bf16(a_h[mf], b_h, acc[mf][nf], 0, 0, 0);
                acc[mf][nf] = __builtin_amdgcn_mfma_f32_16x16x32_bf16(a_h[mf], b_l, acc[mf][nf], 0, 0, 0);
                acc[mf][nf] = __builtin_amdgcn_mfma_f32_16x16x32_bf16(a_l[mf], b_h, acc[mf][nf], 0, 0, 0);
            }
        }
        __syncthreads();
    }
    // epilogue: write EWt[n][m] (transposed) as bf16 hi/lo
#pragma unroll
    for (int mf = 0; mf < 2; mf++)
#pragma unroll
        for (int nf = 0; nf < 4; nf++) {
            int gn = bn + wn + nf * 16 + l16;
            int gm = bm + wm + mf * 16 + quad * 4;
            ushort4 h4, l4;
            float v0 = acc[mf][nf][0], v1 = acc[mf][nf][1];
            float v2 = acc[mf][nf][2], v3 = acc[mf][nf][3];
            h4.x = f2bf(v0); l4.x = f2bf(v0 - bf2f(h4.x));
            h4.y = f2bf(v1); l4.y = f2bf(v1 - bf2f(h4.y));
            h4.z = f2bf(v2); l4.z = f2bf(v2 - bf2f(h4.z));
            h4.w = f2bf(v3); l4.w = f2bf(v3 - bf2f(h4.w));
            *(ushort4*)&EWt_hi[(size_t)gn * 8192 + gm] = h4;
            *(ushort4*)&EWt_lo[(size_t)gn * 8192 + gm] = l4;
        }
}

// ---------------------------------------------------------------------------
// Stage 2: Zx[5888][512] += x[5888][8150] @ EW (via EWt bf16 hi/lo, split-K).
// grid (46 m-blocks of 128, 2 n-cols of 256, 8 k-chunks of 1024), 512 threads.
// Accumulates with fp32 atomicAdd into zero-initialized Zx.
// ---------------------------------------------------------------------------
__global__ __launch_bounds__(512, 4) void zx_kernel(
    const float* __restrict__ X, const ushort* __restrict__ EWt_hi,
    const ushort* __restrict__ EWt_lo, float* __restrict__ Zx) {
    __shared__ ushort Ah[128 * LSTRIDE], Al[128 * LSTRIDE];
    __shared__ ushort Bh[256 * LSTRIDE], Bl[256 * LSTRIDE];
    int bm = blockIdx.x * 128;
    int bn = blockIdx.y * 256;
    int kc = blockIdx.z * 1024;
    int tid = threadIdx.x;
    int lane = tid & 63, w = tid >> 6;
    int quad = lane >> 4, l16 = lane & 15;
    int wm = (w & 3) * 32, wn = (w >> 2) * 128;

    f32x4 acc[2][8];
#pragma unroll
    for (int a = 0; a < 2; a++)
#pragma unroll
        for (int b = 0; b < 8; b++) acc[a][b] = (f32x4){0.f, 0.f, 0.f, 0.f};

    for (int step = 0; step < 32; step++) {
        int k0 = kc + step * 32;
        // A staging: X[bm+m][k0+kk] fp32 -> hi/lo bf16 (guard k<8150)
#pragma unroll
        for (int r = 0; r < 4; r++) {
            int flat = tid + r * 512;              // 0..2047
            int m = flat >> 4, kk = (flat & 15) * 2;
            int gk = k0 + kk;
            float vx = 0.f, vy = 0.f;
            if (gk + 1 < 8150) {
                float2 v = *(const float2*)&X[(size_t)(bm + m) * 8150 + gk];
                vx = v.x; vy = v.y;
            }
            ushort hx = f2bf(vx), hy = f2bf(vy);
            ushort2 h; h.x = hx; h.y = hy;
            ushort2 l; l.x = f2bf(vx - bf2f(hx)); l.y = f2bf(vy - bf2f(hy));
            *(ushort2*)&Ah[m * LSTRIDE + kk] = h;
            *(ushort2*)&Al[m * LSTRIDE + kk] = l;
        }
        // B staging: EWt rows already bf16; copy 8-elem chunks
#pragma unroll
        for (int r = 0; r < 2; r++) {
            int flat = tid + r * 512;              // 0..1023
            int n = flat >> 2, seg = flat & 3;
            size_t go = (size_t)(bn + n) * 8192 + k0 + seg * 8;
            *(uint4*)&Bh[n * LSTRIDE + seg * 8] = *(const uint4*)&EWt_hi[go];
            *(uint4*)&Bl[n * LSTRIDE + seg * 8] = *(const uint4*)&EWt_lo[go];
        }
        __syncthreads();
        bf16x8 a_h[2], a_l[2];
#pragma unroll
        for (int mf = 0; mf < 2; mf++) {
            int row = wm + mf * 16 + l16;
            a_h[mf] = *(const bf16x8*)&Ah[row * LSTRIDE + quad * 8];
            a_l[mf] = *(const bf16x8*)&Al[row * LSTRIDE + quad * 8];
        }
#pragma unroll
        for (int nf = 0; nf < 8; nf++) {
            int col = wn + nf * 16 + l16;
            bf16x8 b_h = *(const bf16x8*)&Bh[col * LSTRIDE + quad * 8];
            bf16x8 b_l = *(const bf16x8*)&Bl[col * LSTRIDE + quad * 8];
#pragma unroll
            for (int mf = 0; mf < 2; mf++) {
                acc[mf][nf] = __builtin_amdgcn_mfma_f32_16x16x32_bf16(a_h[mf], b_h, acc[mf][nf], 0, 0, 0);
                acc[mf][nf] = __builtin_amdgcn_mfma_f32_16x16x32_bf16(a_h[mf], b_l, acc[mf][nf], 0, 0, 0);
                acc[mf][nf] = __builtin_amdgcn_mfma_f32_16x16x32_bf16(a_l[mf], b_h, acc[mf][nf], 0, 0, 0);
            }
        }
        __syncthreads();
    }
#pragma unroll
    for (int mf = 0; mf < 2; mf++)
#pragma unroll
        for (int nf = 0; nf < 8; nf++) {
            int row = bm + wm + mf * 16 + quad * 4;
            int col = bn + wn + nf * 16 + l16;
#pragma unroll
            for (int i = 0; i < 4; i++)
                atomicAdd(&Zx[(size_t)(row + i) * 512 + col], acc[mf][nf][i]);
        }
}

#define TT 46

__device__ __forceinline__ float sigf(float x) { return 1.f / (1.f + expf(-x)); }

// LayerNorm LSTM recurrence (unchanged from passing baseline).
__global__ __launch_bounds__(256) void lstm_kernel(
    const float* __restrict__ Zx1, const float* __restrict__ Zx2,
    const float* __restrict__ W1, const float* __restrict__ W2,
    const float* __restrict__ lng1, const float* __restrict__ lnb1,
    const float* __restrict__ lng2, const float* __restrict__ lnb2,
    float* __restrict__ o1, float* __restrict__ o2) {
    int lstm = blockIdx.x >> 5;
    int r0 = (blockIdx.x & 31) * 4;
    const float* Zx = lstm ? Zx2 : Zx1;
    const float* Wh = (lstm ? W2 : W1) + 300 * 512;
    const float* g  = lstm ? lng2 : lng1;
    const float* bb = lstm ? lnb2 : lnb1;
    float* obuf = lstm ? o2 : o1;

    __shared__ __align__(16) float hs[4][128];
    __shared__ __align__(16) float cs[4][128];
    __shared__ __align__(16) float zb[4][512];
    __shared__ float mu[4][4], rs[4][4], cmu[4], crs[4];

    int tid = threadIdx.x;
    for (int i = tid; i < 512; i += 256) {
        hs[i >> 7][i & 127] = 0.f;
        cs[i >> 7][i & 127] = 0.f;
    }
    __syncthreads();

    for (int t = 0; t < TT; t++) {
        int c0 = tid * 2;
        float2 acc[4];
#pragma unroll
        for (int r = 0; r < 4; r++)
            acc[r] = *(const float2*)&Zx[((size_t)(r0 + r) * TT + t) * 512 + c0];
        for (int k = 0; k < 128; k += 4) {
            float4 h4[4];
#pragma unroll
            for (int r = 0; r < 4; r++) h4[r] = *(const float4*)&hs[r][k];
#pragma unroll
            for (int kk = 0; kk < 4; kk++) {
                float2 wv = *(const float2*)&Wh[(size_t)(k + kk) * 512 + c0];
#pragma unroll
                for (int r = 0; r < 4; r++) {
                    float hk = ((const float*)&h4[r])[kk];
                    acc[r].x = fmaf(hk, wv.x, acc[r].x);
                    acc[r].y = fmaf(hk, wv.y, acc[r].y);
                }
            }
        }
#pragma unroll
        for (int r = 0; r < 4; r++) {
            zb[r][c0] = acc[r].x;
            zb[r][c0 + 1] = acc[r].y;
        }
        __syncthreads();

        {
            int grp = tid >> 4;
            int row = grp >> 2, gate = grp & 3;
            int l = tid & 15;
            float s = 0.f, ss = 0.f;
#pragma unroll
            for (int j = 0; j < 8; j++) {
                float v = zb[row][gate * 128 + l + j * 16];
                s += v; ss += v * v;
            }
#pragma unroll
            for (int off = 1; off < 16; off <<= 1) {
                s += __shfl_xor(s, off);
                ss += __shfl_xor(ss, off);
            }
            if (l == 0) {
                float m_ = s * (1.f / 128.f);
                mu[row][gate] = m_;
                rs[row][gate] = rsqrtf(ss * (1.f / 128.f) - m_ * m_ + 1e-12f);
            }
        }
        __syncthreads();

        float ogate[2];
#pragma unroll
        for (int ii = 0; ii < 2; ii++) {
            int idx = tid + ii * 256;
            int row = idx >> 7, col = idx & 127;
            float i_g = (zb[row][col]       - mu[row][0]) * rs[row][0] * g[0 * 128 + col] + bb[0 * 128 + col];
            float j_g = (zb[row][128 + col] - mu[row][1]) * rs[row][1] * g[1 * 128 + col] + bb[1 * 128 + col];
            float f_g = (zb[row][256 + col] - mu[row][2]) * rs[row][2] * g[2 * 128 + col] + bb[2 * 128 + col];
            float o_g = (zb[row][384 + col] - mu[row][3]) * rs[row][3] * g[3 * 128 + col] + bb[3 * 128 + col];
            float nc = cs[row][col] * sigf(f_g + 1.f) + sigf(i_g) * fmaxf(j_g, 0.f);
            cs[row][col] = nc;
            ogate[ii] = o_g;
        }
        __syncthreads();

        {
            int ww = tid >> 6, l = tid & 63;
            float v0 = cs[ww][l], v1 = cs[ww][l + 64];
            float s = v0 + v1, ss = v0 * v0 + v1 * v1;
#pragma unroll
            for (int off = 1; off < 64; off <<= 1) {
                s += __shfl_xor(s, off);
                ss += __shfl_xor(ss, off);
            }
            if (l == 0) {
                float m_ = s * (1.f / 128.f);
                cmu[ww] = m_;
                crs[ww] = rsqrtf(ss * (1.f / 128.f) - m_ * m_ + 1e-12f);
            }
        }
        __syncthreads();

#pragma unroll
        for (int ii = 0; ii < 2; ii++) {
            int idx = tid + ii * 256;
            int row = idx >> 7, col = idx & 127;
            float lnc = (cs[row][col] - cmu[row]) * crs[row] * g[4 * 128 + col] + bb[4 * 128 + col];
            float hv = fmaxf(lnc, 0.f) * sigf(ogate[ii]);
            hs[row][col] = hv;
            obuf[((size_t)(r0 + row) * TT + t) * 128 + col] = hv;
        }
        __syncthreads();
    }
}

// Attention (unchanged).
__global__ __launch_bounds__(256) void attn_kernel(
    const float* __restrict__ o1, const float* __restrict__ o2,
    const float* __restrict__ v1, const float* __restrict__ v2,
    const float* __restrict__ Wo1, const float* __restrict__ Wo2,
    const float* __restrict__ bo1, const float* __restrict__ bo2,
    float* __restrict__ acat) {
    int lstm = blockIdx.x >> 7;
    int b = blockIdx.x & 127;
    const float* o  = (lstm ? o2 : o1) + (size_t)b * TT * 128;
    const float* v  = lstm ? v2 : v1;
    const float* Wo = lstm ? Wo2 : Wo1;
    const float* bo = lstm ? bo2 : bo1;
    __shared__ float sc[64];
    __shared__ float ctx[128];
    int tid = threadIdx.x;
    if (tid < TT) {
        float s = 0.f;
        for (int h = 0; h < 128; h++) s = fmaf(o[tid * 128 + h], v[h], s);
        sc[tid] = s;
    }
    __syncthreads();
    if (tid < 64) {
        float x = (tid < TT) ? sc[tid] : -1e30f;
        float m = x;
#pragma unroll
        for (int off = 1; off < 64; off <<= 1) m = fmaxf(m, __shfl_xor(m, off));
        float e = (tid < TT) ? expf(x - m) : 0.f;
        float s = e;
#pragma unroll
        for (int off = 1; off < 64; off <<= 1) s += __shfl_xor(s, off);
        if (tid < TT) sc[tid] = e / s;
    }
    __syncthreads();
    if (tid < 128) {
        float s = 0.f;
        for (int t = 0; t < TT; t++) s = fmaf(sc[t], o[t * 128 + tid], s);
        ctx[tid] = s;
    }
    __syncthreads();
#pragma unroll
    for (int j = 0; j < 2; j++) {
        int n = tid * 2 + j;
        float s = bo[n];
        for (int h = 0; h < 128; h++) s = fmaf(ctx[h], Wo[h * 512 + n], s);
        acat[(size_t)b * 1024 + lstm * 512 + n] = fmaxf(s, 0.f);
    }
}

// Final MLP (unchanged).
__global__ __launch_bounds__(256) void final_kernel(
    const float* __restrict__ acat, const float* __restrict__ Wh,
    const float* __restrict__ bh, const float* __restrict__ Wout,
    const float* __restrict__ bout, float* __restrict__ out) {
    int b = blockIdx.x;
    __shared__ float ain[1024];
    __shared__ float hid[512];
    __shared__ float red[4];
    int tid = threadIdx.x;
    for (int i = tid; i < 1024; i += 256) ain[i] = acat[(size_t)b * 1024 + i];
    __syncthreads();
#pragma unroll
    for (int j = 0; j < 2; j++) {
        int n = tid * 2 + j;
        float s = bh[n];
        for (int k = 0; k < 1024; k++) s = fmaf(ain[k], Wh[(size_t)k * 512 + n], s);
        hid[n] = fmaxf(s, 0.f);
    }
    __syncthreads();
    for (int j = 0; j < 2; j++) {
        float p = 0.f;
        for (int k = tid; k < 512; k += 256) p = fmaf(hid[k], Wout[k * 2 + j], p);
#pragma unroll
        for (int off = 1; off < 64; off <<= 1) p += __shfl_xor(p, off);
        if ((tid & 63) == 0) red[tid >> 6] = p;
        __syncthreads();
        if (tid == 0) out[b * 2 + j] = red[0] + red[1] + red[2] + red[3] + bout[j];
        __syncthreads();
    }
}

extern "C" void kernel_launch(void* const* d_in, const int* in_sizes, int n_in,
                              void* d_out, int out_size, void* d_ws, size_t ws_size,
                              hipStream_t stream) {
    const float* x1      = (const float*)d_in[0];
    const float* x2      = (const float*)d_in[1];
    const float* embed1  = (const float*)d_in[2];
    const float* embed2  = (const float*)d_in[3];
    const float* W_lstm1 = (const float*)d_in[4];
    const float* W_lstm2 = (const float*)d_in[5];
    const float* lng1    = (const float*)d_in[6];
    const float* lnb1    = (const float*)d_in[7];
    const float* lng2    = (const float*)d_in[8];
    const float* lnb2    = (const float*)d_in[9];
    const float* attn_v1 = (const float*)d_in[10];
    const float* attn_Wo1= (const float*)d_in[11];
    const float* attn_bo1= (const float*)d_in[12];
    const float* attn_v2 = (const float*)d_in[13];
    const float* attn_Wo2= (const float*)d_in[14];
    const float* attn_bo2= (const float*)d_in[15];
    const float* W_h     = (const float*)d_in[16];
    const float* b_h     = (const float*)d_in[17];
    const float* W_out   = (const float*)d_in[18];
    const float* b_out   = (const float*)d_in[19];
    float* out = (float*)d_out;

    // Workspace layout
    ushort* EWt_hi = (ushort*)d_ws;                      // 512*8192 bf16
    ushort* EWt_lo = EWt_hi + (size_t)512 * 8192;        // 512*8192 bf16
    float* Zx1 = (float*)(EWt_lo + (size_t)512 * 8192);  // 5888*512 f32
    float* Zx2 = Zx1 + 3014656;
    float* o1  = Zx2 + 3014656;                          // 128*46*128
    float* o2  = o1 + 753664;
    float* acat = o2 + 753664;                           // 128*1024
    // total ~47.5 MB

    hipMemsetAsync(Zx1, 0, (size_t)3014656 * 4, stream);
    hipMemsetAsync(Zx2, 0, (size_t)3014656 * 4, stream);

    // Branch 1
    ew_kernel<<<dim3(64, 4), 512, 0, stream>>>(embed1, W_lstm1, EWt_hi, EWt_lo);
    zx_kernel<<<dim3(46, 2, 8), 512, 0, stream>>>(x1, EWt_hi, EWt_lo, Zx1);
    // Branch 2 (reuses EWt buffers; stream-ordered)
    ew_kernel<<<dim3(64, 4), 512, 0, stream>>>(embed2, W_lstm2, EWt_hi, EWt_lo);
    zx_kernel<<<dim3(46, 2, 8), 512, 0, stream>>>(x2, EWt_hi, EWt_lo, Zx2);

    lstm_kernel<<<64, 256, 0, stream>>>(Zx1, Zx2, W_lstm1, W_lstm2,
                                        lng1, lnb1, lng2, lnb2, o1, o2);
    attn_kernel<<<256, 256, 0, stream>>>(o1, o2, attn_v1, attn_v2,
                                         attn_Wo1, attn_Wo2, attn_bo1, attn_bo2, acat);
    final_kernel<<<128, 256, 0, stream>>>(acat, W_h, b_h, W_out, b_out, out);
}